// Round 4
// baseline (208.797 us; speedup 1.0000x reference)
//
#include <hip/hip_runtime.h>
#include <hip/hip_bf16.h>
#include <cstdint>

// MultiHeadAttention: out = ( softmax(causal((X Wq^T)(X Wk^T)^T / 8)) (X Wv^T) ) Wo^T
// B=2, S=2048, D_MODEL=1024, H=16, D_HEAD=64. All MFMA bf16, accum fp32.
//
// Workspace layout (64 MB):
//  [0,8M)    Qp  bf16 [16][4096][64]  per-head packed, pre-scaled by log2e/8
//  [8,16M)   Kp  bf16 [16][4096][64]  per-head packed
//  [16,24M)  Vt  bf16 [1024][4096]    V transposed (row = h*64+d, col = token)
//  [24,32M)  Ctx bf16 [4096][1024]
//  [32,56M)  Xq/Xk/Xv bf16 inputs
//  [56,64M)  Wq/Wk/Wv/Wo bf16 weights

typedef unsigned short u16;
typedef u16 u16x4 __attribute__((ext_vector_type(4)));
typedef u16 u16x8 __attribute__((ext_vector_type(8)));
typedef unsigned u32x4 __attribute__((ext_vector_type(4)));
typedef __bf16 bf16x8 __attribute__((ext_vector_type(8)));
typedef float f32x4 __attribute__((ext_vector_type(4)));
typedef float f32x16 __attribute__((ext_vector_type(16)));

#define S_LEN 2048
#define DM 1024
#define NH 16
#define DH 64
#define BATCH 2
#define MTOT (BATCH*S_LEN)   // 4096

__device__ __forceinline__ u16 f2bf(float f) {
  union { float f; unsigned u; } v; v.f = f;
  unsigned r = v.u + 0x7FFFu + ((v.u >> 16) & 1u);   // RNE
  return (u16)(r >> 16);
}

__device__ __forceinline__ f32x4 mfma16(u16x8 a, u16x8 b, f32x4 c) {
  return __builtin_amdgcn_mfma_f32_16x16x32_bf16(
      __builtin_bit_cast(bf16x8, a), __builtin_bit_cast(bf16x8, b), c, 0, 0, 0);
}
__device__ __forceinline__ f32x16 mfma32(u16x8 a, u16x8 b, f32x16 c) {
  return __builtin_amdgcn_mfma_f32_32x32x16_bf16(
      __builtin_bit_cast(bf16x8, a), __builtin_bit_cast(bf16x8, b), c, 0, 0, 0);
}
__device__ __forceinline__ unsigned cvtpk_bf16(float lo, float hi) {
  unsigned r;
  asm("v_cvt_pk_bf16_f32 %0, %1, %2" : "=v"(r) : "v"(lo), "v"(hi));
  return r;
}
__device__ __forceinline__ void permswap(unsigned &a, unsigned &b) {
  asm volatile("v_permlane32_swap_b32 %0, %1" : "+v"(a), "+v"(b));
}
// async global -> LDS, 16B per lane; LDS dest = wave-uniform base + lane*16
__device__ __forceinline__ void gload16(const u16* g, u16* l) {
  __builtin_amdgcn_global_load_lds(
      (const __attribute__((address_space(1))) unsigned int*)g,
      (__attribute__((address_space(3))) unsigned int*)l, 16, 0, 0);
}

// ---------------------------------------------------------------- fp32->bf16
__global__ __launch_bounds__(256) void cvt_kernel(
    const float* __restrict__ s0, const float* __restrict__ s1,
    const float* __restrict__ s2, const float* __restrict__ s3,
    const float* __restrict__ s4, const float* __restrict__ s5,
    const float* __restrict__ s6,
    u16* __restrict__ d0, u16* __restrict__ d1, u16* __restrict__ d2,
    u16* __restrict__ d3, u16* __restrict__ d4, u16* __restrict__ d5,
    u16* __restrict__ d6) {
  const int y = blockIdx.y;
  const float* s; u16* d; int n;
  switch (y) {
    case 0: s = s0; d = d0; n = MTOT*DM; break;
    case 1: s = s1; d = d1; n = MTOT*DM; break;
    case 2: s = s2; d = d2; n = MTOT*DM; break;
    case 3: s = s3; d = d3; n = DM*DM;   break;
    case 4: s = s4; d = d4; n = DM*DM;   break;
    case 5: s = s5; d = d5; n = DM*DM;   break;
    default: s = s6; d = d6; n = DM*DM;  break;
  }
  int i = (blockIdx.x * 256 + threadIdx.x) * 4;
  if (i >= n) return;
  f32x4 v = *(const f32x4*)&s[i];
  u16x4 o;
  o[0] = f2bf(v[0]); o[1] = f2bf(v[1]); o[2] = f2bf(v[2]); o[3] = f2bf(v[3]);
  *(u16x4*)&d[i] = o;
}

// ---------------------------------------------------------------- GEMM C=A*B^T
// m97 structure: 128x128 tile, BK=32, 4 waves (2x2), global_load_lds width-16
// staging into LINEAR LDS [128][32], 2 barriers per K-step, 4x4 16x16x32 MFMA.
#define BM 128
#define BN 128
#define BKK 32

template<int MODE>
__device__ __forceinline__ void gemm_core(const u16* __restrict__ A,
                                          const u16* __restrict__ Bw,
                                          void* __restrict__ Cv,
                                          int K, float scale) {
  __shared__ u16 As[BM * BKK];
  __shared__ u16 Bs[BN * BKK];
  const int tid  = threadIdx.x;
  const int lane = tid & 63, w = tid >> 6;
  const int g = lane >> 4, r16 = lane & 15;
  const int wm = w >> 1, wn = w & 1;
  const int rowBase = blockIdx.y * BM;
  const int colBase = blockIdx.x * BN;
  f32x4 acc[4][4] = {};
  const int srow = lane >> 2;
  const int skc  = (lane & 3) * 8;
  const u16* gA[2]; const u16* gB[2]; u16* lA[2]; u16* lB[2];
#pragma unroll
  for (int j = 0; j < 2; j++) {
    const int c = w * 2 + j;
    gA[j] = &A [(size_t)(rowBase + c * 16 + srow) * K + skc];
    gB[j] = &Bw[(size_t)(colBase + c * 16 + srow) * K + skc];
    lA[j] = &As[c * 512];
    lB[j] = &Bs[c * 512];
  }
  for (int k0 = 0; k0 < K; k0 += BKK) {
    __syncthreads();
#pragma unroll
    for (int j = 0; j < 2; j++) {
      gload16(gA[j] + k0, lA[j]);
      gload16(gB[j] + k0, lB[j]);
    }
    __syncthreads();
    u16x8 af[4], bfv[4];
#pragma unroll
    for (int i = 0; i < 4; i++) af[i]  = *(const u16x8*)&As[(wm*64 + i*16 + r16) * BKK + g*8];
#pragma unroll
    for (int j = 0; j < 4; j++) bfv[j] = *(const u16x8*)&Bs[(wn*64 + j*16 + r16) * BKK + g*8];
    __builtin_amdgcn_s_setprio(1);
#pragma unroll
    for (int i = 0; i < 4; i++)
#pragma unroll
      for (int j = 0; j < 4; j++) acc[i][j] = mfma16(af[i], bfv[j], acc[i][j]);
    __builtin_amdgcn_s_setprio(0);
  }
  // C/D layout: col = lane&15, row = 4*(lane>>4)+reg
#pragma unroll
  for (int i = 0; i < 4; i++) {
#pragma unroll
    for (int j = 0; j < 4; j++) {
      int row = rowBase + wm*64 + i*16 + 4*g;
      int col = colBase + wn*64 + j*16 + r16;
      if (MODE == 0) {
        u16* O = (u16*)Cv;
        int head = col >> 6, d = col & 63;
#pragma unroll
        for (int r = 0; r < 4; r++)
          O[((size_t)head * MTOT + row + r) * DH + d] = f2bf(acc[i][j][r] * scale);
      } else if (MODE == 1) {
        u16x4 o;
#pragma unroll
        for (int r = 0; r < 4; r++) o[r] = f2bf(acc[i][j][r]);
        *(u16x4*)&((u16*)Cv)[(size_t)col * MTOT + row] = o;
      } else {
#pragma unroll
        for (int r = 0; r < 4; r++)
          ((float*)Cv)[(size_t)(row + r) * DM + col] = acc[i][j][r];
      }
    }
  }
}

__global__ __launch_bounds__(256) void qkv_proj_kernel(
    const u16* __restrict__ Xq, const u16* __restrict__ Xk, const u16* __restrict__ Xv,
    const u16* __restrict__ Wq, const u16* __restrict__ Wk, const u16* __restrict__ Wv,
    u16* __restrict__ Qp, u16* __restrict__ Kp, u16* __restrict__ Vt) {
  const int z = blockIdx.z;
  // Q pre-scaled by (1/sqrt(64)) * log2(e) -> softmax in exp2 domain
  if (z == 0)      gemm_core<0>(Xq, Wq, Qp, DM, 0.125f * 1.44269504f);
  else if (z == 1) gemm_core<0>(Xk, Wk, Kp, DM, 1.0f);
  else             gemm_core<1>(Xv, Wv, Vt, DM, 1.0f);
}

__global__ __launch_bounds__(256) void out_proj_kernel(
    const u16* __restrict__ Ctx, const u16* __restrict__ Wo, float* __restrict__ Out) {
  gemm_core<2>(Ctx, Wo, Out, DM, 1.0f);
}

// ---------------------------------------------------------------- flash attn
// Grid 1024 blocks, 4 waves/block. Block owns (bh, 64 q-rows); wave (qsb,kvh)
// owns 32 q-rows x interleaved kv tiles (t % 2 == kvh). Partial (m,l,ctx)
// per wave, merged via LDS at the end (flash-decoding split). Doubles wave
// count vs round 3 -> 4 waves/SIMD of work for latency hiding.
// Swapped QK^T, exp2-domain softmax, reg-dbuf K prefetch, V under softmax,
// T12 cvt_pk+permlane, T13 defer-max, T5 setprio, XCD-bijective remap.

#define LOADK(KF, T)                                                           \
  {                                                                            \
    const int kv0_ = (T) * 64;                                                 \
    _Pragma("unroll")                                                          \
    for (int ds = 0; ds < 4; ds++) {                                           \
      KF[2*ds]   = *(const u16x8*)&Kbase[(size_t)(kv0_ + q32) * DH + ds*16 + hi*8];      \
      KF[2*ds+1] = *(const u16x8*)&Kbase[(size_t)(kv0_ + 32 + q32) * DH + ds*16 + hi*8]; \
    }                                                                          \
  }

#define TILE_BODY(KF, T)                                                       \
  {                                                                            \
    const int kv0 = (T) * 64;                                                  \
    f32x16 s0 = {}, s1 = {};                                                   \
    __builtin_amdgcn_s_setprio(1);                                             \
    _Pragma("unroll")                                                          \
    for (int ds = 0; ds < 4; ds++) {                                           \
      s0 = mfma32(KF[2*ds],   qf[ds], s0);                                     \
      s1 = mfma32(KF[2*ds+1], qf[ds], s1);                                     \
    }                                                                          \
    __builtin_amdgcn_s_setprio(0);                                             \
    u16x8 vf[8];                                                               \
    _Pragma("unroll")                                                          \
    for (int ks = 0; ks < 4; ks++) {                                           \
      vf[2*ks]   = *(const u16x8*)&Vbase[(size_t)q32 * MTOT        + kv0 + ks*16 + hi*8]; \
      vf[2*ks+1] = *(const u16x8*)&Vbase[(size_t)(32 + q32) * MTOT + kv0 + ks*16 + hi*8]; \
    }                                                                          \
    if ((T) == ntiles - 1) {                                                   \
      const int qg = qbase + q32;                                              \
      _Pragma("unroll")                                                        \
      for (int r = 0; r < 16; r++) {                                           \
        int kvr = kv0 + (r & 3) + 8 * (r >> 2) + 4 * hi;                       \
        if (kvr > qg)      s0[r] = -1e30f;                                     \
        if (kvr + 32 > qg) s1[r] = -1e30f;                                     \
      }                                                                        \
    }                                                                          \
    float pmax = s0[0];                                                        \
    _Pragma("unroll")                                                          \
    for (int r = 1; r < 16; r++) pmax = fmaxf(pmax, s0[r]);                    \
    _Pragma("unroll")                                                          \
    for (int r = 0; r < 16; r++) pmax = fmaxf(pmax, s1[r]);                    \
    pmax = fmaxf(pmax, __shfl_xor(pmax, 32, 64));                              \
    if (__ballot(pmax > m + 11.5f)) {   /* defer-max, THR = 8/ln2 */           \
      float mnew = fmaxf(m, pmax);                                             \
      float alpha = exp2f(m - mnew);                                           \
      l *= alpha; m = mnew;                                                    \
      _Pragma("unroll")                                                        \
      for (int r = 0; r < 16; r++) {                                           \
        float fsc = __shfl(alpha, (r & 3) + 8 * (r >> 2) + 4 * hi, 64);        \
        ctx0[r] *= fsc; ctx1[r] *= fsc;                                        \
      }                                                                        \
    }                                                                          \
    float psum = 0.f;                                                          \
    _Pragma("unroll")                                                          \
    for (int r = 0; r < 16; r++) { s0[r] = exp2f(s0[r] - m); psum += s0[r]; }  \
    _Pragma("unroll")                                                          \
    for (int r = 0; r < 16; r++) { s1[r] = exp2f(s1[r] - m); psum += s1[r]; }  \
    psum += __shfl_xor(psum, 32, 64);                                          \
    l += psum;                                                                 \
    u16x8 pa[4];                                                               \
    _Pragma("unroll")                                                          \
    for (int tt = 0; tt < 2; tt++) {                                           \
      unsigned pk[8];                                                          \
      _Pragma("unroll")                                                        \
      for (int i = 0; i < 8; i++)                                              \
        pk[i] = cvtpk_bf16(tt ? s1[2*i] : s0[2*i], tt ? s1[2*i+1] : s0[2*i+1]);\
      permswap(pk[0], pk[2]); permswap(pk[1], pk[3]);                          \
      permswap(pk[4], pk[6]); permswap(pk[5], pk[7]);                          \
      u32x4 w0 = {pk[0], pk[1], pk[2], pk[3]};                                 \
      u32x4 w1 = {pk[4], pk[5], pk[6], pk[7]};                                 \
      pa[2*tt]   = __builtin_bit_cast(u16x8, w0);                              \
      pa[2*tt+1] = __builtin_bit_cast(u16x8, w1);                              \
    }                                                                          \
    __builtin_amdgcn_s_setprio(1);                                             \
    _Pragma("unroll")                                                          \
    for (int ks = 0; ks < 4; ks++) {                                           \
      ctx0 = mfma32(pa[ks], vf[2*ks],   ctx0);                                 \
      ctx1 = mfma32(pa[ks], vf[2*ks+1], ctx1);                                 \
    }                                                                          \
    __builtin_amdgcn_s_setprio(0);                                             \
  }

__global__ __launch_bounds__(256, 3) void attn_kernel(const u16* __restrict__ Qp,
                                                      const u16* __restrict__ Kp,
                                                      const u16* __restrict__ Vt,
                                                      u16* __restrict__ Ctx) {
  __shared__ float mlds[2][2][64];     // [qsb][kvh][lane] partial max
  __shared__ float llds[2][64];        // wave kvh=1 scaled l
  __shared__ float clds[2][32][64];    // wave kvh=1 scaled ctx (r<16: ctx0)
  const int tid = threadIdx.x;
  const int lane = tid & 63, wid = tid >> 6;
  const int qsb = wid >> 1, kvh = wid & 1;
  const int q32 = lane & 31, hi = lane >> 5;
  // XCD-bijective remap (assumes XCD = flat % 8): each XCD owns 4 (b,h)
  // pairs (2MB K+V inside its 4MB L2); heavy q-chunks dispatch first.
  const int flat = blockIdx.x;                 // 0..1023
  const int xcd = flat & 7, idx = flat >> 3;   // idx 0..127
  const int bh = xcd * 4 + (idx & 3);
  const int qc = 31 - (idx >> 2);              // 0..31, heavy first
  const int bb = bh >> 4, h = bh & 15;
  const int qbase = qc * 64 + qsb * 32;

  const u16* Qbase = Qp + (size_t)(h * MTOT + bb * S_LEN) * DH;
  const u16* Kbase = Kp + (size_t)(h * MTOT + bb * S_LEN) * DH;
  const u16* Vbase = Vt + (size_t)(h * DH) * MTOT + bb * S_LEN;

  u16x8 qf[4];
#pragma unroll
  for (int ds = 0; ds < 4; ds++)
    qf[ds] = *(const u16x8*)&Qbase[(size_t)(qbase + q32) * DH + ds * 16 + hi * 8];

  f32x16 ctx0 = {}, ctx1 = {};
  float m = -3.0e38f, l = 0.f;
  const int ntiles = ((qbase + 31) >> 6) + 1;

  // wave processes tiles t = kvh, kvh+2, ... ; K reg-double-buffered
  u16x8 kA[8], kB[8];
  int t = kvh;
  if (t < ntiles) {
    LOADK(kA, t);
    for (; t < ntiles; t += 4) {
      if (t + 2 < ntiles) LOADK(kB, t + 2);
      TILE_BODY(kA, t);
      if (t + 2 < ntiles) {
        if (t + 4 < ntiles) LOADK(kA, t + 4);
        TILE_BODY(kB, t + 2);
      }
    }
  }

  // ---- merge the two kv-halves of each q-sub-block via LDS ----
  mlds[qsb][kvh][lane] = m;
  __syncthreads();
  const float mo = mlds[qsb][kvh ^ 1][lane];
  const float M = fmaxf(m, mo);
  const float alpha = exp2f(m - M);   // 0 when this wave had no tiles
  l *= alpha;
  if (kvh == 1) {
#pragma unroll
    for (int r = 0; r < 16; r++) {
      float fa = __shfl(alpha, (r & 3) + 8 * (r >> 2) + 4 * hi, 64);
      clds[qsb][r][lane]      = ctx0[r] * fa;
      clds[qsb][16 + r][lane] = ctx1[r] * fa;
    }
    llds[qsb][lane] = l;
  }
  __syncthreads();
  if (kvh == 0) {
    const float L = l + llds[qsb][lane];
    const float linv = 1.f / L;
#pragma unroll
    for (int r = 0; r < 16; r++) {
      int qr = (r & 3) + 8 * (r >> 2) + 4 * hi;
      float fa = __shfl(alpha, qr, 64);
      float fl = __shfl(linv, qr, 64);
      float o0 = ctx0[r] * fa + clds[qsb][r][lane];
      float o1 = ctx1[r] * fa + clds[qsb][16 + r][lane];
      size_t grow = (size_t)(bb * S_LEN + qbase + qr) * DM + h * DH;
      Ctx[grow + q32]      = f2bf(o0 * fl);
      Ctx[grow + 32 + q32] = f2bf(o1 * fl);
    }
  }
}

// ---------------------------------------------------------------- launch
extern "C" void kernel_launch(void* const* d_in, const int* in_sizes, int n_in,
                              void* d_out, int out_size, void* d_ws, size_t ws_size,
                              hipStream_t stream) {
  const float* q_in = (const float*)d_in[0];
  const float* k_in = (const float*)d_in[1];
  const float* v_in = (const float*)d_in[2];
  // d_in[3] = causal mask, unused (causality structural)
  const float* wq = (const float*)d_in[4];
  const float* wk = (const float*)d_in[5];
  const float* wv = (const float*)d_in[6];
  const float* wo = (const float*)d_in[7];

  char* ws = (char*)d_ws;
  const size_t MB = 1024ull * 1024ull;
  u16* Qp  = (u16*)(ws + 0  * MB);
  u16* Kp  = (u16*)(ws + 8  * MB);
  u16* Vt  = (u16*)(ws + 16 * MB);
  u16* Ctx = (u16*)(ws + 24 * MB);
  u16* Xq  = (u16*)(ws + 32 * MB);
  u16* Xk  = (u16*)(ws + 40 * MB);
  u16* Xv  = (u16*)(ws + 48 * MB);
  u16* Wqb = (u16*)(ws + 56 * MB);
  u16* Wkb = (u16*)(ws + 58 * MB);
  u16* Wvb = (u16*)(ws + 60 * MB);
  u16* Wob = (u16*)(ws + 62 * MB);

  cvt_kernel<<<dim3(4096, 7, 1), 256, 0, stream>>>(
      q_in, k_in, v_in, wq, wk, wv, wo, Xq, Xk, Xv, Wqb, Wkb, Wvb, Wob);
  qkv_proj_kernel<<<dim3(DM / BN, MTOT / BM, 3), 256, 0, stream>>>(
      Xq, Xk, Xv, Wqb, Wkb, Wvb, Qp, Kp, Vt);
  attn_kernel<<<dim3(1024), 256, 0, stream>>>(Qp, Kp, Vt, Ctx);
  out_proj_kernel<<<dim3(DM / BN, MTOT / BM), 256, 0, stream>>>(Ctx, Wob, (float*)d_out);
}

// Round 5
// 152.305 us; speedup vs baseline: 1.3709x; 1.3709x over previous
//
#include <hip/hip_runtime.h>
#include <hip/hip_bf16.h>
#include <cstdint>

// MultiHeadAttention: out = ( softmax(causal((X Wq^T)(X Wk^T)^T / 8)) (X Wv^T) ) Wo^T
// B=2, S=2048, D_MODEL=1024, H=16, D_HEAD=64. All MFMA bf16, accum fp32.
//
// Workspace layout (64 MB):
//  [0,8M)    Qp  bf16 [16][4096][64]  per-head packed, pre-scaled by log2e/8
//  [8,16M)   Kp  bf16 [16][4096][64]  per-head packed
//  [16,24M)  Vt  bf16 [1024][4096]    V transposed (row = h*64+d, col = token)
//  [24,32M)  Ctx bf16 [4096][1024]
//  [32,56M)  Xq/Xk/Xv bf16 inputs
//  [56,64M)  Wq/Wk/Wv/Wo bf16 weights

typedef unsigned short u16;
typedef u16 u16x4 __attribute__((ext_vector_type(4)));
typedef u16 u16x8 __attribute__((ext_vector_type(8)));
typedef unsigned u32x4 __attribute__((ext_vector_type(4)));
typedef __bf16 bf16x8 __attribute__((ext_vector_type(8)));
typedef float f32x4 __attribute__((ext_vector_type(4)));
typedef float f32x16 __attribute__((ext_vector_type(16)));

#define S_LEN 2048
#define DM 1024
#define NH 16
#define DH 64
#define BATCH 2
#define MTOT (BATCH*S_LEN)   // 4096

__device__ __forceinline__ u16 f2bf(float f) {
  union { float f; unsigned u; } v; v.f = f;
  unsigned r = v.u + 0x7FFFu + ((v.u >> 16) & 1u);   // RNE
  return (u16)(r >> 16);
}

__device__ __forceinline__ f32x4 mfma16(u16x8 a, u16x8 b, f32x4 c) {
  return __builtin_amdgcn_mfma_f32_16x16x32_bf16(
      __builtin_bit_cast(bf16x8, a), __builtin_bit_cast(bf16x8, b), c, 0, 0, 0);
}
__device__ __forceinline__ f32x16 mfma32(u16x8 a, u16x8 b, f32x16 c) {
  return __builtin_amdgcn_mfma_f32_32x32x16_bf16(
      __builtin_bit_cast(bf16x8, a), __builtin_bit_cast(bf16x8, b), c, 0, 0, 0);
}
__device__ __forceinline__ unsigned cvtpk_bf16(float lo, float hi) {
  unsigned r;
  asm("v_cvt_pk_bf16_f32 %0, %1, %2" : "=v"(r) : "v"(lo), "v"(hi));
  return r;
}
__device__ __forceinline__ void permswap(unsigned &a, unsigned &b) {
  asm volatile("v_permlane32_swap_b32 %0, %1" : "+v"(a), "+v"(b));
}
// async global -> LDS, 16B per lane; LDS dest = wave-uniform base + lane*16
__device__ __forceinline__ void gload16(const u16* g, u16* l) {
  __builtin_amdgcn_global_load_lds(
      (const __attribute__((address_space(1))) unsigned int*)g,
      (__attribute__((address_space(3))) unsigned int*)l, 16, 0, 0);
}

// ---------------------------------------------------------------- fp32->bf16
__global__ __launch_bounds__(256) void cvt_kernel(
    const float* __restrict__ s0, const float* __restrict__ s1,
    const float* __restrict__ s2, const float* __restrict__ s3,
    const float* __restrict__ s4, const float* __restrict__ s5,
    const float* __restrict__ s6,
    u16* __restrict__ d0, u16* __restrict__ d1, u16* __restrict__ d2,
    u16* __restrict__ d3, u16* __restrict__ d4, u16* __restrict__ d5,
    u16* __restrict__ d6) {
  const int y = blockIdx.y;
  const float* s; u16* d; int n;
  switch (y) {
    case 0: s = s0; d = d0; n = MTOT*DM; break;
    case 1: s = s1; d = d1; n = MTOT*DM; break;
    case 2: s = s2; d = d2; n = MTOT*DM; break;
    case 3: s = s3; d = d3; n = DM*DM;   break;
    case 4: s = s4; d = d4; n = DM*DM;   break;
    case 5: s = s5; d = d5; n = DM*DM;   break;
    default: s = s6; d = d6; n = DM*DM;  break;
  }
  int i = (blockIdx.x * 256 + threadIdx.x) * 4;
  if (i >= n) return;
  f32x4 v = *(const f32x4*)&s[i];
  u16x4 o;
  o[0] = f2bf(v[0]); o[1] = f2bf(v[1]); o[2] = f2bf(v[2]); o[3] = f2bf(v[3]);
  *(u16x4*)&d[i] = o;
}

// ---------------------------------------------------------------- GEMM C=A*B^T
// m97 structure: 128x128 tile, BK=32, 4 waves (2x2), global_load_lds width-16
// staging into LINEAR LDS [128][32], 2 barriers per K-step, 4x4 16x16x32 MFMA.
#define BM 128
#define BN 128
#define BKK 32

template<int MODE>
__device__ __forceinline__ void gemm_core(const u16* __restrict__ A,
                                          const u16* __restrict__ Bw,
                                          void* __restrict__ Cv,
                                          int K, float scale) {
  __shared__ u16 As[BM * BKK];
  __shared__ u16 Bs[BN * BKK];
  const int tid  = threadIdx.x;
  const int lane = tid & 63, w = tid >> 6;
  const int g = lane >> 4, r16 = lane & 15;
  const int wm = w >> 1, wn = w & 1;
  const int rowBase = blockIdx.y * BM;
  const int colBase = blockIdx.x * BN;
  f32x4 acc[4][4] = {};
  const int srow = lane >> 2;
  const int skc  = (lane & 3) * 8;
  const u16* gA[2]; const u16* gB[2]; u16* lA[2]; u16* lB[2];
#pragma unroll
  for (int j = 0; j < 2; j++) {
    const int c = w * 2 + j;
    gA[j] = &A [(size_t)(rowBase + c * 16 + srow) * K + skc];
    gB[j] = &Bw[(size_t)(colBase + c * 16 + srow) * K + skc];
    lA[j] = &As[c * 512];
    lB[j] = &Bs[c * 512];
  }
  for (int k0 = 0; k0 < K; k0 += BKK) {
    __syncthreads();
#pragma unroll
    for (int j = 0; j < 2; j++) {
      gload16(gA[j] + k0, lA[j]);
      gload16(gB[j] + k0, lB[j]);
    }
    __syncthreads();
    u16x8 af[4], bfv[4];
#pragma unroll
    for (int i = 0; i < 4; i++) af[i]  = *(const u16x8*)&As[(wm*64 + i*16 + r16) * BKK + g*8];
#pragma unroll
    for (int j = 0; j < 4; j++) bfv[j] = *(const u16x8*)&Bs[(wn*64 + j*16 + r16) * BKK + g*8];
    __builtin_amdgcn_s_setprio(1);
#pragma unroll
    for (int i = 0; i < 4; i++)
#pragma unroll
      for (int j = 0; j < 4; j++) acc[i][j] = mfma16(af[i], bfv[j], acc[i][j]);
    __builtin_amdgcn_s_setprio(0);
  }
  // C/D layout: col = lane&15, row = 4*(lane>>4)+reg
#pragma unroll
  for (int i = 0; i < 4; i++) {
#pragma unroll
    for (int j = 0; j < 4; j++) {
      int row = rowBase + wm*64 + i*16 + 4*g;
      int col = colBase + wn*64 + j*16 + r16;
      if (MODE == 0) {
        u16* O = (u16*)Cv;
        int head = col >> 6, d = col & 63;
#pragma unroll
        for (int r = 0; r < 4; r++)
          O[((size_t)head * MTOT + row + r) * DH + d] = f2bf(acc[i][j][r] * scale);
      } else if (MODE == 1) {
        u16x4 o;
#pragma unroll
        for (int r = 0; r < 4; r++) o[r] = f2bf(acc[i][j][r]);
        *(u16x4*)&((u16*)Cv)[(size_t)col * MTOT + row] = o;
      } else {
#pragma unroll
        for (int r = 0; r < 4; r++)
          ((float*)Cv)[(size_t)(row + r) * DM + col] = acc[i][j][r];
      }
    }
  }
}

__global__ __launch_bounds__(256) void qkv_proj_kernel(
    const u16* __restrict__ Xq, const u16* __restrict__ Xk, const u16* __restrict__ Xv,
    const u16* __restrict__ Wq, const u16* __restrict__ Wk, const u16* __restrict__ Wv,
    u16* __restrict__ Qp, u16* __restrict__ Kp, u16* __restrict__ Vt) {
  const int z = blockIdx.z;
  // Q pre-scaled by (1/sqrt(64)) * log2(e) -> softmax in exp2 domain
  if (z == 0)      gemm_core<0>(Xq, Wq, Qp, DM, 0.125f * 1.44269504f);
  else if (z == 1) gemm_core<0>(Xk, Wk, Kp, DM, 1.0f);
  else             gemm_core<1>(Xv, Wv, Vt, DM, 1.0f);
}

__global__ __launch_bounds__(256) void out_proj_kernel(
    const u16* __restrict__ Ctx, const u16* __restrict__ Wo, float* __restrict__ Out) {
  gemm_core<2>(Ctx, Wo, Out, DM, 1.0f);
}

// ---------------------------------------------------------------- flash attn
// Grid 1024 blocks, 4 waves/block. Block owns (bh, 64 q-rows); wave (qsb,kvh)
// owns 32 q-rows x interleaved kv tiles (t % 2 == kvh), merged via LDS.
// Single K register buffer: next tile's K is prefetched into kA right after
// the QK^T MFMAs consume it (kA dead there) -> same latency cover as a
// double-buffer at 32 fewer VGPRs. launch_bounds(256,2): NO forced spill
// (round 4 post-mortem: (256,3) forced VGPR=84 -> 330MB scratch traffic).

#define LOADK(KF, T)                                                           \
  {                                                                            \
    const int kv0_ = (T) * 64;                                                 \
    _Pragma("unroll")                                                          \
    for (int ds = 0; ds < 4; ds++) {                                           \
      KF[2*ds]   = *(const u16x8*)&Kbase[(size_t)(kv0_ + q32) * DH + ds*16 + hi*8];      \
      KF[2*ds+1] = *(const u16x8*)&Kbase[(size_t)(kv0_ + 32 + q32) * DH + ds*16 + hi*8]; \
    }                                                                          \
  }

#define TILE_BODY(T, PF)                                                       \
  {                                                                            \
    const int kv0 = (T) * 64;                                                  \
    f32x16 s0 = {}, s1 = {};                                                   \
    __builtin_amdgcn_s_setprio(1);                                             \
    _Pragma("unroll")                                                          \
    for (int ds = 0; ds < 4; ds++) {                                           \
      s0 = mfma32(kA[2*ds],   qf[ds], s0);                                     \
      s1 = mfma32(kA[2*ds+1], qf[ds], s1);                                     \
    }                                                                          \
    __builtin_amdgcn_s_setprio(0);                                             \
    if (PF) LOADK(kA, (T) + 2);        /* kA dead after QK^T -> prefetch */    \
    u16x8 vf[8];                                                               \
    _Pragma("unroll")                                                          \
    for (int ks = 0; ks < 4; ks++) {                                           \
      vf[2*ks]   = *(const u16x8*)&Vbase[(size_t)q32 * MTOT        + kv0 + ks*16 + hi*8]; \
      vf[2*ks+1] = *(const u16x8*)&Vbase[(size_t)(32 + q32) * MTOT + kv0 + ks*16 + hi*8]; \
    }                                                                          \
    if ((T) == ntiles - 1) {                                                   \
      const int qg = qbase + q32;                                              \
      _Pragma("unroll")                                                        \
      for (int r = 0; r < 16; r++) {                                           \
        int kvr = kv0 + (r & 3) + 8 * (r >> 2) + 4 * hi;                       \
        if (kvr > qg)      s0[r] = -1e30f;                                     \
        if (kvr + 32 > qg) s1[r] = -1e30f;                                     \
      }                                                                        \
    }                                                                          \
    float pmax = s0[0];                                                        \
    _Pragma("unroll")                                                          \
    for (int r = 1; r < 16; r++) pmax = fmaxf(pmax, s0[r]);                    \
    _Pragma("unroll")                                                          \
    for (int r = 0; r < 16; r++) pmax = fmaxf(pmax, s1[r]);                    \
    pmax = fmaxf(pmax, __shfl_xor(pmax, 32, 64));                              \
    if (__ballot(pmax > m + 11.5f)) {   /* defer-max, THR = 8/ln2 */           \
      float mnew = fmaxf(m, pmax);                                             \
      float alpha = exp2f(m - mnew);                                           \
      l *= alpha; m = mnew;                                                    \
      _Pragma("unroll")                                                        \
      for (int r = 0; r < 16; r++) {                                           \
        float fsc = __shfl(alpha, (r & 3) + 8 * (r >> 2) + 4 * hi, 64);        \
        ctx0[r] *= fsc; ctx1[r] *= fsc;                                        \
      }                                                                        \
    }                                                                          \
    float psum = 0.f;                                                          \
    _Pragma("unroll")                                                          \
    for (int r = 0; r < 16; r++) { s0[r] = exp2f(s0[r] - m); psum += s0[r]; }  \
    _Pragma("unroll")                                                          \
    for (int r = 0; r < 16; r++) { s1[r] = exp2f(s1[r] - m); psum += s1[r]; }  \
    psum += __shfl_xor(psum, 32, 64);                                          \
    l += psum;                                                                 \
    u16x8 pa[4];                                                               \
    _Pragma("unroll")                                                          \
    for (int tt = 0; tt < 2; tt++) {                                           \
      unsigned pk[8];                                                          \
      _Pragma("unroll")                                                        \
      for (int i = 0; i < 8; i++)                                              \
        pk[i] = cvtpk_bf16(tt ? s1[2*i] : s0[2*i], tt ? s1[2*i+1] : s0[2*i+1]);\
      permswap(pk[0], pk[2]); permswap(pk[1], pk[3]);                          \
      permswap(pk[4], pk[6]); permswap(pk[5], pk[7]);                          \
      u32x4 w0 = {pk[0], pk[1], pk[2], pk[3]};                                 \
      u32x4 w1 = {pk[4], pk[5], pk[6], pk[7]};                                 \
      pa[2*tt]   = __builtin_bit_cast(u16x8, w0);                              \
      pa[2*tt+1] = __builtin_bit_cast(u16x8, w1);                              \
    }                                                                          \
    __builtin_amdgcn_s_setprio(1);                                             \
    _Pragma("unroll")                                                          \
    for (int ks = 0; ks < 4; ks++) {                                           \
      ctx0 = mfma32(pa[ks], vf[2*ks],   ctx0);                                 \
      ctx1 = mfma32(pa[ks], vf[2*ks+1], ctx1);                                 \
    }                                                                          \
    __builtin_amdgcn_s_setprio(0);                                             \
  }

__global__ __launch_bounds__(256, 2) void attn_kernel(const u16* __restrict__ Qp,
                                                      const u16* __restrict__ Kp,
                                                      const u16* __restrict__ Vt,
                                                      u16* __restrict__ Ctx) {
  __shared__ float mlds[2][2][64];     // [qsb][kvh][lane] partial max
  __shared__ float llds[2][64];        // wave kvh=1 scaled l
  __shared__ float clds[2][32][64];    // wave kvh=1 scaled ctx (r<16: ctx0)
  const int tid = threadIdx.x;
  const int lane = tid & 63, wid = tid >> 6;
  const int qsb = wid >> 1, kvh = wid & 1;
  const int q32 = lane & 31, hi = lane >> 5;
  // XCD-bijective remap (assumes XCD = flat % 8): each XCD owns 4 (b,h)
  // pairs (2MB K+V inside its 4MB L2); heavy q-chunks dispatch first.
  const int flat = blockIdx.x;                 // 0..1023
  const int xcd = flat & 7, idx = flat >> 3;   // idx 0..127
  const int bh = xcd * 4 + (idx & 3);
  const int qc = 31 - (idx >> 2);              // 0..31, heavy first
  const int bb = bh >> 4, h = bh & 15;
  const int qbase = qc * 64 + qsb * 32;

  const u16* Qbase = Qp + (size_t)(h * MTOT + bb * S_LEN) * DH;
  const u16* Kbase = Kp + (size_t)(h * MTOT + bb * S_LEN) * DH;
  const u16* Vbase = Vt + (size_t)(h * DH) * MTOT + bb * S_LEN;

  u16x8 qf[4];
#pragma unroll
  for (int ds = 0; ds < 4; ds++)
    qf[ds] = *(const u16x8*)&Qbase[(size_t)(qbase + q32) * DH + ds * 16 + hi * 8];

  f32x16 ctx0 = {}, ctx1 = {};
  float m = -3.0e38f, l = 0.f;
  const int ntiles = ((qbase + 31) >> 6) + 1;

  // wave processes tiles t = kvh, kvh+2, ...; K prefetched in-body into kA
  u16x8 kA[8];
  if (kvh < ntiles) {
    LOADK(kA, kvh);
    for (int t = kvh; t < ntiles; t += 2) {
      TILE_BODY(t, (t + 2 < ntiles));
    }
  }

  // ---- merge the two kv-halves of each q-sub-block via LDS ----
  mlds[qsb][kvh][lane] = m;
  __syncthreads();
  const float mo = mlds[qsb][kvh ^ 1][lane];
  const float M = fmaxf(m, mo);
  const float alpha = exp2f(m - M);   // 0 when this wave had no tiles
  l *= alpha;
  if (kvh == 1) {
#pragma unroll
    for (int r = 0; r < 16; r++) {
      float fa = __shfl(alpha, (r & 3) + 8 * (r >> 2) + 4 * hi, 64);
      clds[qsb][r][lane]      = ctx0[r] * fa;
      clds[qsb][16 + r][lane] = ctx1[r] * fa;
    }
    llds[qsb][lane] = l;
  }
  __syncthreads();
  if (kvh == 0) {
    const float L = l + llds[qsb][lane];
    const float linv = 1.f / L;
#pragma unroll
    for (int r = 0; r < 16; r++) {
      int qr = (r & 3) + 8 * (r >> 2) + 4 * hi;
      float fa = __shfl(alpha, qr, 64);
      float fl = __shfl(linv, qr, 64);
      float o0 = ctx0[r] * fa + clds[qsb][r][lane];
      float o1 = ctx1[r] * fa + clds[qsb][16 + r][lane];
      size_t grow = (size_t)(bb * S_LEN + qbase + qr) * DM + h * DH;
      Ctx[grow + q32]      = f2bf(o0 * fl);
      Ctx[grow + 32 + q32] = f2bf(o1 * fl);
    }
  }
}

// ---------------------------------------------------------------- launch
extern "C" void kernel_launch(void* const* d_in, const int* in_sizes, int n_in,
                              void* d_out, int out_size, void* d_ws, size_t ws_size,
                              hipStream_t stream) {
  const float* q_in = (const float*)d_in[0];
  const float* k_in = (const float*)d_in[1];
  const float* v_in = (const float*)d_in[2];
  // d_in[3] = causal mask, unused (causality structural)
  const float* wq = (const float*)d_in[4];
  const float* wk = (const float*)d_in[5];
  const float* wv = (const float*)d_in[6];
  const float* wo = (const float*)d_in[7];

  char* ws = (char*)d_ws;
  const size_t MB = 1024ull * 1024ull;
  u16* Qp  = (u16*)(ws + 0  * MB);
  u16* Kp  = (u16*)(ws + 8  * MB);
  u16* Vt  = (u16*)(ws + 16 * MB);
  u16* Ctx = (u16*)(ws + 24 * MB);
  u16* Xq  = (u16*)(ws + 32 * MB);
  u16* Xk  = (u16*)(ws + 40 * MB);
  u16* Xv  = (u16*)(ws + 48 * MB);
  u16* Wqb = (u16*)(ws + 56 * MB);
  u16* Wkb = (u16*)(ws + 58 * MB);
  u16* Wvb = (u16*)(ws + 60 * MB);
  u16* Wob = (u16*)(ws + 62 * MB);

  cvt_kernel<<<dim3(4096, 7, 1), 256, 0, stream>>>(
      q_in, k_in, v_in, wq, wk, wv, wo, Xq, Xk, Xv, Wqb, Wkb, Wvb, Wob);
  qkv_proj_kernel<<<dim3(DM / BN, MTOT / BM, 3), 256, 0, stream>>>(
      Xq, Xk, Xv, Wqb, Wkb, Wvb, Qp, Kp, Vt);
  attn_kernel<<<dim3(1024), 256, 0, stream>>>(Qp, Kp, Vt, Ctx);
  out_proj_kernel<<<dim3(DM / BN, MTOT / BM), 256, 0, stream>>>(Ctx, Wob, (float*)d_out);
}

// Round 6
// 151.068 us; speedup vs baseline: 1.3821x; 1.0082x over previous
//
#include <hip/hip_runtime.h>
#include <hip/hip_bf16.h>
#include <cstdint>

// MultiHeadAttention: out = ( softmax(causal((X Wq^T)(X Wk^T)^T / 8)) (X Wv^T) ) Wo^T
// B=2, S=2048, D_MODEL=1024, H=16, D_HEAD=64. All MFMA bf16, accum fp32.
//
// Workspace layout (64 MB):
//  [0,8M)    Qp  bf16 [16][4096][64]  per-head packed, pre-scaled by log2e/8
//  [8,16M)   Kp  bf16 [16][4096][64]  per-head packed
//  [16,24M)  Vt  bf16 [1024][4096]    V transposed (row = h*64+d, col = token)
//  [24,32M)  Ctx bf16 [4096][1024]
//  [32,56M)  Xq/Xk/Xv bf16 inputs
//  [56,64M)  Wq/Wk/Wv/Wo bf16 weights

typedef unsigned short u16;
typedef u16 u16x4 __attribute__((ext_vector_type(4)));
typedef u16 u16x8 __attribute__((ext_vector_type(8)));
typedef unsigned u32x4 __attribute__((ext_vector_type(4)));
typedef __bf16 bf16x8 __attribute__((ext_vector_type(8)));
typedef float f32x4 __attribute__((ext_vector_type(4)));
typedef float f32x16 __attribute__((ext_vector_type(16)));

#define S_LEN 2048
#define DM 1024
#define NH 16
#define DH 64
#define BATCH 2
#define MTOT (BATCH*S_LEN)   // 4096

__device__ __forceinline__ u16 f2bf(float f) {
  union { float f; unsigned u; } v; v.f = f;
  unsigned r = v.u + 0x7FFFu + ((v.u >> 16) & 1u);   // RNE
  return (u16)(r >> 16);
}

__device__ __forceinline__ f32x4 mfma16(u16x8 a, u16x8 b, f32x4 c) {
  return __builtin_amdgcn_mfma_f32_16x16x32_bf16(
      __builtin_bit_cast(bf16x8, a), __builtin_bit_cast(bf16x8, b), c, 0, 0, 0);
}
__device__ __forceinline__ f32x16 mfma32(u16x8 a, u16x8 b, f32x16 c) {
  return __builtin_amdgcn_mfma_f32_32x32x16_bf16(
      __builtin_bit_cast(bf16x8, a), __builtin_bit_cast(bf16x8, b), c, 0, 0, 0);
}
__device__ __forceinline__ unsigned cvtpk_bf16(float lo, float hi) {
  unsigned r;
  asm("v_cvt_pk_bf16_f32 %0, %1, %2" : "=v"(r) : "v"(lo), "v"(hi));
  return r;
}
__device__ __forceinline__ void permswap(unsigned &a, unsigned &b) {
  asm volatile("v_permlane32_swap_b32 %0, %1" : "+v"(a), "+v"(b));
}
// async global -> LDS, 16B per lane; LDS dest = wave-uniform base + lane*16
__device__ __forceinline__ void gload16(const u16* g, u16* l) {
  __builtin_amdgcn_global_load_lds(
      (const __attribute__((address_space(1))) unsigned int*)g,
      (__attribute__((address_space(3))) unsigned int*)l, 16, 0, 0);
}

// ---------------------------------------------------------------- fp32->bf16
__global__ __launch_bounds__(256) void cvt_kernel(
    const float* __restrict__ s0, const float* __restrict__ s1,
    const float* __restrict__ s2, const float* __restrict__ s3,
    const float* __restrict__ s4, const float* __restrict__ s5,
    const float* __restrict__ s6,
    u16* __restrict__ d0, u16* __restrict__ d1, u16* __restrict__ d2,
    u16* __restrict__ d3, u16* __restrict__ d4, u16* __restrict__ d5,
    u16* __restrict__ d6) {
  const int y = blockIdx.y;
  const float* s; u16* d; int n;
  switch (y) {
    case 0: s = s0; d = d0; n = MTOT*DM; break;
    case 1: s = s1; d = d1; n = MTOT*DM; break;
    case 2: s = s2; d = d2; n = MTOT*DM; break;
    case 3: s = s3; d = d3; n = DM*DM;   break;
    case 4: s = s4; d = d4; n = DM*DM;   break;
    case 5: s = s5; d = d5; n = DM*DM;   break;
    default: s = s6; d = d6; n = DM*DM;  break;
  }
  int i = (blockIdx.x * 256 + threadIdx.x) * 4;
  if (i >= n) return;
  f32x4 v = *(const f32x4*)&s[i];
  u16x4 o;
  o[0] = f2bf(v[0]); o[1] = f2bf(v[1]); o[2] = f2bf(v[2]); o[3] = f2bf(v[3]);
  *(u16x4*)&d[i] = o;
}

// ---------------------------------------------------------------- GEMM C=A*B^T
// m97 structure: 128x128 tile, BK=32, 4 waves (2x2), global_load_lds width-16
// staging into LINEAR LDS [128][32], 2 barriers per K-step, 4x4 16x16x32 MFMA.
#define BM 128
#define BN 128
#define BKK 32

template<int MODE>
__device__ __forceinline__ void gemm_core(const u16* __restrict__ A,
                                          const u16* __restrict__ Bw,
                                          void* __restrict__ Cv,
                                          int K, float scale) {
  __shared__ u16 As[BM * BKK];
  __shared__ u16 Bs[BN * BKK];
  const int tid  = threadIdx.x;
  const int lane = tid & 63, w = tid >> 6;
  const int g = lane >> 4, r16 = lane & 15;
  const int wm = w >> 1, wn = w & 1;
  const int rowBase = blockIdx.y * BM;
  const int colBase = blockIdx.x * BN;
  f32x4 acc[4][4] = {};
  const int srow = lane >> 2;
  const int skc  = (lane & 3) * 8;
  const u16* gA[2]; const u16* gB[2]; u16* lA[2]; u16* lB[2];
#pragma unroll
  for (int j = 0; j < 2; j++) {
    const int c = w * 2 + j;
    gA[j] = &A [(size_t)(rowBase + c * 16 + srow) * K + skc];
    gB[j] = &Bw[(size_t)(colBase + c * 16 + srow) * K + skc];
    lA[j] = &As[c * 512];
    lB[j] = &Bs[c * 512];
  }
  for (int k0 = 0; k0 < K; k0 += BKK) {
    __syncthreads();
#pragma unroll
    for (int j = 0; j < 2; j++) {
      gload16(gA[j] + k0, lA[j]);
      gload16(gB[j] + k0, lB[j]);
    }
    __syncthreads();
    u16x8 af[4], bfv[4];
#pragma unroll
    for (int i = 0; i < 4; i++) af[i]  = *(const u16x8*)&As[(wm*64 + i*16 + r16) * BKK + g*8];
#pragma unroll
    for (int j = 0; j < 4; j++) bfv[j] = *(const u16x8*)&Bs[(wn*64 + j*16 + r16) * BKK + g*8];
    __builtin_amdgcn_s_setprio(1);
#pragma unroll
    for (int i = 0; i < 4; i++)
#pragma unroll
      for (int j = 0; j < 4; j++) acc[i][j] = mfma16(af[i], bfv[j], acc[i][j]);
    __builtin_amdgcn_s_setprio(0);
  }
  // C/D layout: col = lane&15, row = 4*(lane>>4)+reg
#pragma unroll
  for (int i = 0; i < 4; i++) {
#pragma unroll
    for (int j = 0; j < 4; j++) {
      int row = rowBase + wm*64 + i*16 + 4*g;
      int col = colBase + wn*64 + j*16 + r16;
      if (MODE == 0) {
        u16* O = (u16*)Cv;
        int head = col >> 6, d = col & 63;
#pragma unroll
        for (int r = 0; r < 4; r++)
          O[((size_t)head * MTOT + row + r) * DH + d] = f2bf(acc[i][j][r] * scale);
      } else if (MODE == 1) {
        u16x4 o;
#pragma unroll
        for (int r = 0; r < 4; r++) o[r] = f2bf(acc[i][j][r]);
        *(u16x4*)&((u16*)Cv)[(size_t)col * MTOT + row] = o;
      } else {
#pragma unroll
        for (int r = 0; r < 4; r++)
          ((float*)Cv)[(size_t)(row + r) * DM + col] = acc[i][j][r];
      }
    }
  }
}

__global__ __launch_bounds__(256) void qkv_proj_kernel(
    const u16* __restrict__ Xq, const u16* __restrict__ Xk, const u16* __restrict__ Xv,
    const u16* __restrict__ Wq, const u16* __restrict__ Wk, const u16* __restrict__ Wv,
    u16* __restrict__ Qp, u16* __restrict__ Kp, u16* __restrict__ Vt) {
  const int z = blockIdx.z;
  // Q pre-scaled by (1/sqrt(64)) * log2(e) -> softmax in exp2 domain
  if (z == 0)      gemm_core<0>(Xq, Wq, Qp, DM, 0.125f * 1.44269504f);
  else if (z == 1) gemm_core<0>(Xk, Wk, Kp, DM, 1.0f);
  else             gemm_core<1>(Xv, Wv, Vt, DM, 1.0f);
}

__global__ __launch_bounds__(256) void out_proj_kernel(
    const u16* __restrict__ Ctx, const u16* __restrict__ Wo, float* __restrict__ Out) {
  gemm_core<2>(Ctx, Wo, Out, DM, 1.0f);
}

// ---------------------------------------------------------------- flash attn
// Grid 2048 blocks, 4 waves/block. Block owns (bh, 32 q-rows); wave kvh
// (0..3) processes kv tiles t % 4 == kvh, partial (m,l,ctx) merged 4-way
// via LDS (flash-decoding split). 8 blocks/CU queued (4 resident at
// VGPR~108) -> load-balance slack the round-5 1024-block grid lacked.
// Swapped QK^T, exp2 softmax, in-place K prefetch (kA dead after QK^T),
// V under softmax, T12 cvt_pk+permlane, T13 defer-max, T5 setprio,
// XCD-bijective remap. launch_bounds(256,2): no forced spill (round-4
// post-mortem: (256,3) forced VGPR=84 -> 330MB scratch traffic).

#define LOADK(KF, T)                                                           \
  {                                                                            \
    const int kv0_ = (T) * 64;                                                 \
    _Pragma("unroll")                                                          \
    for (int ds = 0; ds < 4; ds++) {                                           \
      KF[2*ds]   = *(const u16x8*)&Kbase[(size_t)(kv0_ + q32) * DH + ds*16 + hi*8];      \
      KF[2*ds+1] = *(const u16x8*)&Kbase[(size_t)(kv0_ + 32 + q32) * DH + ds*16 + hi*8]; \
    }                                                                          \
  }

#define TILE_BODY(T, PF)                                                       \
  {                                                                            \
    const int kv0 = (T) * 64;                                                  \
    f32x16 s0 = {}, s1 = {};                                                   \
    __builtin_amdgcn_s_setprio(1);                                             \
    _Pragma("unroll")                                                          \
    for (int ds = 0; ds < 4; ds++) {                                           \
      s0 = mfma32(kA[2*ds],   qf[ds], s0);                                     \
      s1 = mfma32(kA[2*ds+1], qf[ds], s1);                                     \
    }                                                                          \
    __builtin_amdgcn_s_setprio(0);                                             \
    if (PF) LOADK(kA, (T) + 4);        /* kA dead after QK^T -> prefetch */    \
    u16x8 vf[8];                                                               \
    _Pragma("unroll")                                                          \
    for (int ks = 0; ks < 4; ks++) {                                           \
      vf[2*ks]   = *(const u16x8*)&Vbase[(size_t)q32 * MTOT        + kv0 + ks*16 + hi*8]; \
      vf[2*ks+1] = *(const u16x8*)&Vbase[(size_t)(32 + q32) * MTOT + kv0 + ks*16 + hi*8]; \
    }                                                                          \
    if ((T) == ntiles - 1) {                                                   \
      const int qg = qbase + q32;                                              \
      _Pragma("unroll")                                                        \
      for (int r = 0; r < 16; r++) {                                           \
        int kvr = kv0 + (r & 3) + 8 * (r >> 2) + 4 * hi;                       \
        if (kvr > qg)      s0[r] = -1e30f;                                     \
        if (kvr + 32 > qg) s1[r] = -1e30f;                                     \
      }                                                                        \
    }                                                                          \
    float pmax = s0[0];                                                        \
    _Pragma("unroll")                                                          \
    for (int r = 1; r < 16; r++) pmax = fmaxf(pmax, s0[r]);                    \
    _Pragma("unroll")                                                          \
    for (int r = 0; r < 16; r++) pmax = fmaxf(pmax, s1[r]);                    \
    pmax = fmaxf(pmax, __shfl_xor(pmax, 32, 64));                              \
    if (__ballot(pmax > m + 11.5f)) {   /* defer-max, THR = 8/ln2 */           \
      float mnew = fmaxf(m, pmax);                                             \
      float alpha = exp2f(m - mnew);                                           \
      l *= alpha; m = mnew;                                                    \
      _Pragma("unroll")                                                        \
      for (int r = 0; r < 16; r++) {                                           \
        float fsc = __shfl(alpha, (r & 3) + 8 * (r >> 2) + 4 * hi, 64);        \
        ctx0[r] *= fsc; ctx1[r] *= fsc;                                        \
      }                                                                        \
    }                                                                          \
    float psum = 0.f;                                                          \
    _Pragma("unroll")                                                          \
    for (int r = 0; r < 16; r++) { s0[r] = exp2f(s0[r] - m); psum += s0[r]; }  \
    _Pragma("unroll")                                                          \
    for (int r = 0; r < 16; r++) { s1[r] = exp2f(s1[r] - m); psum += s1[r]; }  \
    psum += __shfl_xor(psum, 32, 64);                                          \
    l += psum;                                                                 \
    u16x8 pa[4];                                                               \
    _Pragma("unroll")                                                          \
    for (int tt = 0; tt < 2; tt++) {                                           \
      unsigned pk[8];                                                          \
      _Pragma("unroll")                                                        \
      for (int i = 0; i < 8; i++)                                              \
        pk[i] = cvtpk_bf16(tt ? s1[2*i] : s0[2*i], tt ? s1[2*i+1] : s0[2*i+1]);\
      permswap(pk[0], pk[2]); permswap(pk[1], pk[3]);                          \
      permswap(pk[4], pk[6]); permswap(pk[5], pk[7]);                          \
      u32x4 w0 = {pk[0], pk[1], pk[2], pk[3]};                                 \
      u32x4 w1 = {pk[4], pk[5], pk[6], pk[7]};                                 \
      pa[2*tt]   = __builtin_bit_cast(u16x8, w0);                              \
      pa[2*tt+1] = __builtin_bit_cast(u16x8, w1);                              \
    }                                                                          \
    __builtin_amdgcn_s_setprio(1);                                             \
    _Pragma("unroll")                                                          \
    for (int ks = 0; ks < 4; ks++) {                                           \
      ctx0 = mfma32(pa[ks], vf[2*ks],   ctx0);                                 \
      ctx1 = mfma32(pa[ks], vf[2*ks+1], ctx1);                                 \
    }                                                                          \
    __builtin_amdgcn_s_setprio(0);                                             \
  }

__global__ __launch_bounds__(256, 2) void attn_kernel(const u16* __restrict__ Qp,
                                                      const u16* __restrict__ Kp,
                                                      const u16* __restrict__ Vt,
                                                      u16* __restrict__ Ctx) {
  __shared__ float mlds[4][64];        // per-wave partial max
  __shared__ float llds[3][64];        // waves 1..3 scaled l
  __shared__ float clds[3][32][64];    // waves 1..3 scaled ctx (r<16: ctx0)
  const int tid = threadIdx.x;
  const int lane = tid & 63, kvh = tid >> 6;
  const int q32 = lane & 31, hi = lane >> 5;
  // XCD-bijective remap (assumes XCD = flat % 8): each XCD owns 4 (b,h)
  // pairs (2MB K+V inside its 4MB L2); heavy q-chunks dispatch first.
  const int flat = blockIdx.x;                 // 0..2047
  const int xcd = flat & 7, idx = flat >> 3;   // idx 0..255
  const int bh = xcd * 4 + (idx & 3);
  const int qc = 63 - (idx >> 2);              // 0..63, heavy first
  const int bb = bh >> 4, h = bh & 15;
  const int qbase = qc * 32;

  const u16* Qbase = Qp + (size_t)(h * MTOT + bb * S_LEN) * DH;
  const u16* Kbase = Kp + (size_t)(h * MTOT + bb * S_LEN) * DH;
  const u16* Vbase = Vt + (size_t)(h * DH) * MTOT + bb * S_LEN;

  u16x8 qf[4];
#pragma unroll
  for (int ds = 0; ds < 4; ds++)
    qf[ds] = *(const u16x8*)&Qbase[(size_t)(qbase + q32) * DH + ds * 16 + hi * 8];

  f32x16 ctx0 = {}, ctx1 = {};
  float m = -3.0e38f, l = 0.f;
  const int ntiles = ((qbase + 31) >> 6) + 1;

  // wave kvh processes tiles t = kvh, kvh+4, ...; K prefetched in-body
  u16x8 kA[8];
  if (kvh < ntiles) {
    LOADK(kA, kvh);
    for (int t = kvh; t < ntiles; t += 4) {
      TILE_BODY(t, (t + 4 < ntiles));
    }
  }

  // ---- 4-way merge of kv-split partials via LDS ----
  mlds[kvh][lane] = m;
  __syncthreads();
  const float M = fmaxf(fmaxf(mlds[0][lane], mlds[1][lane]),
                        fmaxf(mlds[2][lane], mlds[3][lane]));
  const float alpha = exp2f(m - M);   // 0 when this wave had no tiles
  l *= alpha;
  if (kvh != 0) {
#pragma unroll
    for (int r = 0; r < 16; r++) {
      float fa = __shfl(alpha, (r & 3) + 8 * (r >> 2) + 4 * hi, 64);
      clds[kvh - 1][r][lane]      = ctx0[r] * fa;
      clds[kvh - 1][16 + r][lane] = ctx1[r] * fa;
    }
    llds[kvh - 1][lane] = l;
  }
  __syncthreads();
  if (kvh == 0) {
    const float L = l + llds[0][lane] + llds[1][lane] + llds[2][lane];
    const float linv = 1.f / L;
#pragma unroll
    for (int r = 0; r < 16; r++) {
      int qr = (r & 3) + 8 * (r >> 2) + 4 * hi;
      float fa = __shfl(alpha, qr, 64);
      float fl = __shfl(linv, qr, 64);
      float o0 = ctx0[r] * fa + clds[0][r][lane] + clds[1][r][lane] + clds[2][r][lane];
      float o1 = ctx1[r] * fa + clds[0][16 + r][lane] + clds[1][16 + r][lane] + clds[2][16 + r][lane];
      size_t grow = (size_t)(bb * S_LEN + qbase + qr) * DM + h * DH;
      Ctx[grow + q32]      = f2bf(o0 * fl);
      Ctx[grow + 32 + q32] = f2bf(o1 * fl);
    }
  }
}

// ---------------------------------------------------------------- launch
extern "C" void kernel_launch(void* const* d_in, const int* in_sizes, int n_in,
                              void* d_out, int out_size, void* d_ws, size_t ws_size,
                              hipStream_t stream) {
  const float* q_in = (const float*)d_in[0];
  const float* k_in = (const float*)d_in[1];
  const float* v_in = (const float*)d_in[2];
  // d_in[3] = causal mask, unused (causality structural)
  const float* wq = (const float*)d_in[4];
  const float* wk = (const float*)d_in[5];
  const float* wv = (const float*)d_in[6];
  const float* wo = (const float*)d_in[7];

  char* ws = (char*)d_ws;
  const size_t MB = 1024ull * 1024ull;
  u16* Qp  = (u16*)(ws + 0  * MB);
  u16* Kp  = (u16*)(ws + 8  * MB);
  u16* Vt  = (u16*)(ws + 16 * MB);
  u16* Ctx = (u16*)(ws + 24 * MB);
  u16* Xq  = (u16*)(ws + 32 * MB);
  u16* Xk  = (u16*)(ws + 40 * MB);
  u16* Xv  = (u16*)(ws + 48 * MB);
  u16* Wqb = (u16*)(ws + 56 * MB);
  u16* Wkb = (u16*)(ws + 58 * MB);
  u16* Wvb = (u16*)(ws + 60 * MB);
  u16* Wob = (u16*)(ws + 62 * MB);

  cvt_kernel<<<dim3(4096, 7, 1), 256, 0, stream>>>(
      q_in, k_in, v_in, wq, wk, wv, wo, Xq, Xk, Xv, Wqb, Wkb, Wvb, Wob);
  qkv_proj_kernel<<<dim3(DM / BN, MTOT / BM, 3), 256, 0, stream>>>(
      Xq, Xk, Xv, Wqb, Wkb, Wvb, Qp, Kp, Vt);
  attn_kernel<<<dim3(2048), 256, 0, stream>>>(Qp, Kp, Vt, Ctx);
  out_proj_kernel<<<dim3(DM / BN, MTOT / BM), 256, 0, stream>>>(Ctx, Wob, (float*)d_out);
}